// Round 1
// baseline (1372.901 us; speedup 1.0000x reference)
//
#include <hip/hip_runtime.h>
#include <hip/hip_bf16.h>
#include <math.h>

#define L_SEQ   16384
#define C_DIM   256
#define N_BATCH 4
#define N_HEAD  8
#define D_H     32
#define M_ROWS  (N_BATCH * L_SEQ)   // 65536
#define KV_SPLIT 16

// ---------------------------------------------------------------------------
// GEMM: C[M,N] = EPI( concat(A1,A2)[M,K] @ B[K,N] )
//   cols < KA read from A1 (row stride sA1); cols >= KA from A2 (stride sA2).
//   EPI: 0 = none, 1 = elu(x)+1, 2 = x*escale, 3 = relu
// Tile 64x64, BK=16, 256 threads, 4x4 per thread, LDS-staged.
// ---------------------------------------------------------------------------
template<int EPI>
__global__ __launch_bounds__(256)
void gemm_f32(const float* __restrict__ A1, const float* __restrict__ A2,
              int KA, int sA1, int sA2,
              const float* __restrict__ B, float* __restrict__ C,
              int N, int K, float escale)
{
    __shared__ __align__(16) float As[16][68];  // [k][m], pad 68 keeps float4 align
    __shared__ __align__(16) float Bs[16][68];  // [k][n]

    const int tid = threadIdx.x;
    const int m0 = blockIdx.y * 64;
    const int n0 = blockIdx.x * 64;
    const int tx = tid & 15;        // n-group
    const int ty = tid >> 4;        // m-group
    const int lka = tid & 15;       // A-load: k within tile
    const int lma = tid >> 4;       // A-load: row base
    const int lnb = tid & 63;       // B-load: col
    const int lkb = tid >> 6;       // B-load: k base

    float acc[4][4] = {};
    const int ktiles = K / 16;

    for (int kt = 0; kt < ktiles; ++kt) {
        __syncthreads();
        // --- stage A tile (64 rows x 16 k) ---
        {
            int kg = kt * 16 + lka;
            const float* Ap; int stride; int col;
            if (kg < KA) { Ap = A1; stride = sA1; col = kg; }
            else         { Ap = A2; stride = sA2; col = kg - KA; }
            #pragma unroll
            for (int p = 0; p < 4; ++p) {
                int m = lma + p * 16;
                As[lka][m] = Ap[(size_t)(m0 + m) * stride + col];
            }
        }
        // --- stage B tile (16 k x 64 cols) ---
        #pragma unroll
        for (int p = 0; p < 4; ++p) {
            int kr = lkb + p * 4;
            Bs[kr][lnb] = B[(size_t)(kt * 16 + kr) * N + n0 + lnb];
        }
        __syncthreads();
        // --- compute ---
        #pragma unroll
        for (int kk = 0; kk < 16; ++kk) {
            float4 a = *(const float4*)&As[kk][ty * 4];
            float4 b = *(const float4*)&Bs[kk][tx * 4];
            float av[4] = {a.x, a.y, a.z, a.w};
            float bv[4] = {b.x, b.y, b.z, b.w};
            #pragma unroll
            for (int i = 0; i < 4; ++i)
                #pragma unroll
                for (int j = 0; j < 4; ++j)
                    acc[i][j] = fmaf(av[i], bv[j], acc[i][j]);
        }
    }

    #pragma unroll
    for (int i = 0; i < 4; ++i) {
        float4 o;
        float* op = (float*)&o;
        #pragma unroll
        for (int j = 0; j < 4; ++j) {
            float v = acc[i][j];
            if (EPI == 1)      v = (v > 0.f) ? (v + 1.f) : expf(v); // elu+1
            else if (EPI == 2) v *= escale;
            else if (EPI == 3) v = (v > 0.f) ? v : 0.f;
            op[j] = v;
        }
        *(float4*)&C[(size_t)(m0 + ty * 4 + i) * N + n0 + tx * 4] = o;
    }
}

// ---------------------------------------------------------------------------
// KV partial: per (n,h,split) block computes partial KV[32][32] and Ksum[32]
// over a chunk of L. Deterministic (no atomics).
// part layout: [N*H*SPLIT][1056]  (1024 = KV tile, +32 = Ksum)
// ---------------------------------------------------------------------------
__global__ __launch_bounds__(256)
void kv_partial(const float* __restrict__ Kf, const float* __restrict__ Vf,
                float* __restrict__ part)
{
    int b = blockIdx.x;
    int s  = b & (KV_SPLIT - 1);
    int nh = b / KV_SPLIT;
    int h  = nh & (N_HEAD - 1);
    int n  = nh / N_HEAD;
    int t  = threadIdx.x;

    __shared__ __align__(16) float Ks[8][D_H];
    __shared__ __align__(16) float Vs[8][D_H];

    const int d   = t >> 3;          // 0..31
    const int dv0 = (t & 7) * 4;     // 0,4,..,28
    const int lr  = t >> 5;          // 0..7 (load row)
    const int dl  = t & 31;          // load col
    const size_t base = ((size_t)n * L_SEQ) * C_DIM + h * D_H;

    float a0 = 0, a1 = 0, a2 = 0, a3 = 0, asum = 0;
    const int CH = L_SEQ / KV_SPLIT; // 1024
    for (int l = s * CH; l < s * CH + CH; l += 8) {
        __syncthreads();
        Ks[lr][dl] = Kf[base + (size_t)(l + lr) * C_DIM + dl];
        Vs[lr][dl] = Vf[base + (size_t)(l + lr) * C_DIM + dl];
        __syncthreads();
        #pragma unroll
        for (int i = 0; i < 8; ++i) {
            float kv = Ks[i][d];
            float4 vv = *(const float4*)&Vs[i][dv0];
            a0 = fmaf(kv, vv.x, a0);
            a1 = fmaf(kv, vv.y, a1);
            a2 = fmaf(kv, vv.z, a2);
            a3 = fmaf(kv, vv.w, a3);
            asum += kv;
        }
    }
    float* p = part + (size_t)b * 1056;
    p[d * D_H + dv0 + 0] = a0;
    p[d * D_H + dv0 + 1] = a1;
    p[d * D_H + dv0 + 2] = a2;
    p[d * D_H + dv0 + 3] = a3;
    if ((t & 7) == 0) p[1024 + d] = asum;
}

__global__ __launch_bounds__(256)
void kv_final(const float* __restrict__ part, float* __restrict__ KV,
              float* __restrict__ Ksum)
{
    int nh = blockIdx.x;   // 0..N*H-1
    int t  = threadIdx.x;
    float ax = 0, ay = 0, az = 0, aw = 0, ssum = 0;
    const float* p0 = part + (size_t)nh * KV_SPLIT * 1056;
    for (int s = 0; s < KV_SPLIT; ++s) {
        const float* p = p0 + (size_t)s * 1056;
        float4 v = *(const float4*)&p[t * 4];
        ax += v.x; ay += v.y; az += v.z; aw += v.w;
        if (t < D_H) ssum += p[1024 + t];
    }
    float4 o = make_float4(ax, ay, az, aw);
    *(float4*)&KV[(size_t)nh * 1024 + t * 4] = o;
    if (t < D_H) Ksum[nh * D_H + t] = ssum;
}

// ---------------------------------------------------------------------------
// attn_msg: one 256-thread block per token. thread t -> (h = t>>5, dv = t&31).
// msg[n,l,h,dv] = (sum_d Q[d] * KV[d][dv]) * Z * L,  Z = 1/(Q . Ksum + eps)
// ---------------------------------------------------------------------------
__global__ __launch_bounds__(256)
void attn_msg(const float* __restrict__ Qf, const float* __restrict__ KV,
              const float* __restrict__ Ksum, float* __restrict__ msg)
{
    int token = blockIdx.x;
    int n = token / L_SEQ;
    int t = threadIdx.x;
    int h = t >> 5, dv = t & 31;

    __shared__ float Qs[C_DIM];
    __shared__ float Ss[C_DIM];
    Qs[t] = Qf[(size_t)token * C_DIM + t];
    Ss[t] = Ksum[(size_t)n * C_DIM + t];
    __syncthreads();

    const float* qrow = &Qs[h * D_H];
    const float* srow = &Ss[h * D_H];
    float zden = 0.f;
    #pragma unroll
    for (int d = 0; d < D_H; ++d) zden = fmaf(qrow[d], srow[d], zden);
    float z = 1.0f / (zden + 1e-6f);

    const float* kvp = KV + (((size_t)n * N_HEAD + h) * D_H) * D_H + dv;
    float sacc = 0.f;
    #pragma unroll
    for (int d = 0; d < D_H; ++d) sacc = fmaf(qrow[d], kvp[d * D_H], sacc);

    msg[(size_t)token * C_DIM + t] = sacc * z * (float)L_SEQ;
}

// ---------------------------------------------------------------------------
// LayerNorm over rows of 256. One wave per row, 4 rows per block.
// ADDX: add residual xres (final output).
// ---------------------------------------------------------------------------
template<bool ADDX>
__global__ __launch_bounds__(256)
void ln_rows(const float* __restrict__ X, const float* __restrict__ g,
             const float* __restrict__ b, const float* __restrict__ xres,
             float* __restrict__ Y)
{
    int row  = blockIdx.x * 4 + (threadIdx.x >> 6);
    int lane = threadIdx.x & 63;
    const float* xr = X + (size_t)row * C_DIM;
    float4 val = *(const float4*)&xr[lane * 4];
    float s  = val.x + val.y + val.z + val.w;
    float s2 = val.x * val.x + val.y * val.y + val.z * val.z + val.w * val.w;
    #pragma unroll
    for (int off = 1; off < 64; off <<= 1) {
        s  += __shfl_xor(s, off);
        s2 += __shfl_xor(s2, off);
    }
    float mu  = s * (1.0f / C_DIM);
    float var = s2 * (1.0f / C_DIM) - mu * mu;
    float rstd = rsqrtf(var + 1e-5f);
    float4 gv = *(const float4*)&g[lane * 4];
    float4 bv = *(const float4*)&b[lane * 4];
    float4 o;
    o.x = (val.x - mu) * rstd * gv.x + bv.x;
    o.y = (val.y - mu) * rstd * gv.y + bv.y;
    o.z = (val.z - mu) * rstd * gv.z + bv.z;
    o.w = (val.w - mu) * rstd * gv.w + bv.w;
    if (ADDX) {
        float4 xv = *(const float4*)&xres[(size_t)row * C_DIM + lane * 4];
        o.x += xv.x; o.y += xv.y; o.z += xv.z; o.w += xv.w;
    }
    *(float4*)&Y[(size_t)row * C_DIM + lane * 4] = o;
}

// ---------------------------------------------------------------------------
extern "C" void kernel_launch(void* const* d_in, const int* in_sizes, int n_in,
                              void* d_out, int out_size, void* d_ws, size_t ws_size,
                              hipStream_t stream)
{
    const float* x  = (const float*)d_in[0];
    const float* Wq = (const float*)d_in[1];
    const float* Wk = (const float*)d_in[2];
    const float* Wv = (const float*)d_in[3];
    const float* Wm = (const float*)d_in[4];
    const float* W1 = (const float*)d_in[5];
    const float* W2 = (const float*)d_in[6];
    const float* g1 = (const float*)d_in[7];
    const float* b1 = (const float*)d_in[8];
    const float* g2 = (const float*)d_in[9];
    const float* b2 = (const float*)d_in[10];
    float* out = (float*)d_out;
    float* ws  = (float*)d_ws;

    const size_t slabF = (size_t)M_ROWS * C_DIM;   // 16,777,216 floats (64 MB)
    float* q    = ws;                  // S0
    float* k    = ws + slabF;          // S1
    float* v    = ws + 2 * slabF;      // S2
    float* KV   = ws + 3 * slabF;                       // 32768 floats
    float* Ksum = KV + (size_t)N_BATCH * N_HEAD * D_H * D_H; // 1024 floats
    float* part = Ksum + (size_t)N_BATCH * N_HEAD * D_H;     // 512*1056 floats
    // Liveness-based reuse:
    float* msg  = k;     // after kv reduction, k slab is free
    float* m1   = v;     // after kv reduction, v slab is free
    float* ln1  = q;     // after attn_msg, q slab is free
    float* hbuf = k;     // 128 MB spanning S1+S2 (msg/m1 dead)
    float* mlp  = q;     // ln1 dead after GEMM2

    dim3 blk(256);
    const float invL = 1.0f / (float)L_SEQ;

    // projections: q = elu(x@Wq)+1, k = elu(x@Wk)+1, v = (x@Wv)/L
    dim3 g256(C_DIM / 64, M_ROWS / 64);
    gemm_f32<1><<<g256, blk, 0, stream>>>(x, x, C_DIM, C_DIM, C_DIM, Wq, q, C_DIM, C_DIM, 1.f);
    gemm_f32<1><<<g256, blk, 0, stream>>>(x, x, C_DIM, C_DIM, C_DIM, Wk, k, C_DIM, C_DIM, 1.f);
    gemm_f32<2><<<g256, blk, 0, stream>>>(x, x, C_DIM, C_DIM, C_DIM, Wv, v, C_DIM, C_DIM, invL);

    // KV = sum_l K^T v  (two-stage, deterministic), Ksum = sum_l K
    kv_partial<<<N_BATCH * N_HEAD * KV_SPLIT, blk, 0, stream>>>(k, v, part);
    kv_final<<<N_BATCH * N_HEAD, blk, 0, stream>>>(part, KV, Ksum);

    // msg = (Q . KV) * Z * L
    attn_msg<<<M_ROWS, blk, 0, stream>>>(q, KV, Ksum, msg);

    // m1 = msg @ Wm ; ln1 = LN(m1)*g1+b1
    gemm_f32<0><<<g256, blk, 0, stream>>>(msg, msg, C_DIM, C_DIM, C_DIM, Wm, m1, C_DIM, C_DIM, 1.f);
    ln_rows<false><<<M_ROWS / 4, blk, 0, stream>>>(m1, g1, b1, nullptr, ln1);

    // h = relu(concat(x, ln1) @ W1)   [M x 512]
    dim3 g512(2 * C_DIM / 64, M_ROWS / 64);
    gemm_f32<3><<<g512, blk, 0, stream>>>(x, ln1, C_DIM, C_DIM, C_DIM, W1, hbuf, 2 * C_DIM, 2 * C_DIM, 1.f);

    // mlp = h @ W2   [M x 256]
    gemm_f32<0><<<g256, blk, 0, stream>>>(hbuf, hbuf, 2 * C_DIM, 2 * C_DIM, 2 * C_DIM, W2, mlp, C_DIM, 2 * C_DIM, 1.f);

    // out = x + LN(mlp)*g2+b2
    ln_rows<true><<<M_ROWS / 4, blk, 0, stream>>>(mlp, g2, b2, x, out);
}

// Round 2
// 351.288 us; speedup vs baseline: 3.9082x; 3.9082x over previous
//
#include <hip/hip_runtime.h>
#include <hip/hip_bf16.h>
#include <math.h>

#define L_SEQ   16384
#define C_DIM   256
#define N_BATCH 4
#define N_HEAD  8
#define D_H     32
#define M_ROWS  (N_BATCH * L_SEQ)   // 65536
#define KV_SPLIT 64

typedef unsigned short u16;
typedef unsigned int   u32;
typedef short s16x8 __attribute__((ext_vector_type(8)));
typedef float f32x4 __attribute__((ext_vector_type(4)));

// ---- bf16 helpers (bit-exact bf16->f32; RNE f32->bf16) ----------------------
__device__ __forceinline__ float bf2f(u32 lo16) { return __uint_as_float(lo16 << 16); }
__device__ __forceinline__ u16 f2bf(float f) {
    u32 u = __float_as_uint(f);
    u32 rb = ((u >> 16) & 1u) + 0x7fffu;
    return (u16)((u + rb) >> 16);
}

// ---- async global->LDS, 16B per lane ---------------------------------------
__device__ __forceinline__ void gl_lds16(const u16* g, u16* l) {
    __builtin_amdgcn_global_load_lds(
        (__attribute__((address_space(1))) void*)g,
        (__attribute__((address_space(3))) void*)l, 16, 0, 0);
}

// ---------------------------------------------------------------------------
// f32 -> bf16 bulk convert (8 elems/thread/iter)
// ---------------------------------------------------------------------------
__global__ __launch_bounds__(256)
void f32_to_bf16_k(const float* __restrict__ in, u16* __restrict__ out, int n8)
{
    int i = blockIdx.x * blockDim.x + threadIdx.x;
    int stride = gridDim.x * blockDim.x;
    for (; i < n8; i += stride) {
        float4 f0 = ((const float4*)in)[(size_t)i * 2];
        float4 f1 = ((const float4*)in)[(size_t)i * 2 + 1];
        uint4 o;
        o.x = (u32)f2bf(f0.x) | ((u32)f2bf(f0.y) << 16);
        o.y = (u32)f2bf(f0.z) | ((u32)f2bf(f0.w) << 16);
        o.z = (u32)f2bf(f1.x) | ((u32)f2bf(f1.y) << 16);
        o.w = (u32)f2bf(f1.z) | ((u32)f2bf(f1.w) << 16);
        ((uint4*)out)[i] = o;
    }
}

// ---------------------------------------------------------------------------
// W[K][N] f32  ->  Wt[N][K] bf16   (32x32 LDS tiles)
// ---------------------------------------------------------------------------
__global__ __launch_bounds__(256)
void w_transpose_bf16(const float* __restrict__ W, u16* __restrict__ Wt, int K, int N)
{
    __shared__ float tile[32][33];
    int n0 = blockIdx.x * 32, k0 = blockIdx.y * 32;
    int tx = threadIdx.x & 31, ty = threadIdx.x >> 5;
    #pragma unroll
    for (int i = 0; i < 32; i += 8)
        tile[ty + i][tx] = W[(size_t)(k0 + ty + i) * N + n0 + tx];
    __syncthreads();
    #pragma unroll
    for (int i = 0; i < 32; i += 8)
        Wt[(size_t)(n0 + ty + i) * K + k0 + tx] = f2bf(tile[tx][ty + i]);
}

// ---------------------------------------------------------------------------
// bf16 MFMA GEMM (m97 structure): C[M,N] = EPI( concat(A1,A2)[M,K] @ B[K,N] )
// B supplied TRANSPOSED: Bt[N][K] bf16. Tile 128x128, BK=32, 4 waves,
// each wave 64x64 via 4x4 of 16x16x32 MFMA. Outputs bf16.
// EPI: 0=none, 1=elu+1, 2=x*escale, 3=relu
// ---------------------------------------------------------------------------
template<int EPI>
__global__ __launch_bounds__(256)
void gemm_bf16(const u16* __restrict__ A1, const u16* __restrict__ A2,
               int KA, int sA1, int sA2,
               const u16* __restrict__ Bt, int ldb,
               u16* __restrict__ C, int N, int K, float escale)
{
    __shared__ __align__(16) u16 As[128 * 32];
    __shared__ __align__(16) u16 Bs[128 * 32];

    const int tid = threadIdx.x;
    const int m0 = blockIdx.y * 128;
    const int n0 = blockIdx.x * 128;
    const int w = tid >> 6, lane = tid & 63;
    const int wr = w >> 1, wc = w & 1;
    const int g = lane >> 4, r = lane & 15;

    f32x4 acc[4][4] = {};

    const int ktiles = K / 32;
    for (int kt = 0; kt < ktiles; ++kt) {
        __syncthreads();
        #pragma unroll
        for (int i = 0; i < 2; ++i) {
            int li  = i * 256 + tid;
            int row = li >> 2, kc = li & 3;
            // A tile: rows m0+row, k = kt*32 + kc*8 .. +7
            int kg = kt * 32 + kc * 8;
            const u16* Ap = (kg < KA) ? A1 : A2;
            int stride    = (kg < KA) ? sA1 : sA2;
            int col       = (kg < KA) ? kg  : kg - KA;
            gl_lds16(Ap + (size_t)(m0 + row) * stride + col, &As[li * 8]);
            // B tile: Bt rows n0+row (n), same k decomposition
            gl_lds16(Bt + (size_t)(n0 + row) * ldb + kt * 32 + kc * 8, &Bs[li * 8]);
        }
        __syncthreads();

        s16x8 a[4], b[4];
        #pragma unroll
        for (int mi = 0; mi < 4; ++mi)
            a[mi] = *(const s16x8*)&As[(wr * 64 + mi * 16 + r) * 32 + g * 8];
        #pragma unroll
        for (int ni = 0; ni < 4; ++ni)
            b[ni] = *(const s16x8*)&Bs[(wc * 64 + ni * 16 + r) * 32 + g * 8];
        #pragma unroll
        for (int mi = 0; mi < 4; ++mi)
            #pragma unroll
            for (int ni = 0; ni < 4; ++ni)
                asm volatile("v_mfma_f32_16x16x32_bf16 %0, %1, %2, %0"
                             : "+v"(acc[mi][ni]) : "v"(a[mi]), "v"(b[ni]));
    }

    // MFMA -> VALU read hazard cover
    asm volatile("s_nop 7");
    asm volatile("s_nop 7");
    asm volatile("s_nop 7");

    #pragma unroll
    for (int mi = 0; mi < 4; ++mi) {
        #pragma unroll
        for (int ni = 0; ni < 4; ++ni) {
            #pragma unroll
            for (int j = 0; j < 4; ++j) {
                float v = acc[mi][ni][j];
                if (EPI == 1)      v = (v > 0.f) ? (v + 1.f) : __expf(v);
                else if (EPI == 2) v *= escale;
                else if (EPI == 3) v = (v > 0.f) ? v : 0.f;
                int row = m0 + wr * 64 + mi * 16 + g * 4 + j;
                int col = n0 + wc * 64 + ni * 16 + r;
                C[(size_t)row * N + col] = f2bf(v);
            }
        }
    }
}

// ---------------------------------------------------------------------------
// KV partial over L-chunks: KV[32][32] += K^T v ; Ksum[32] += K. f32 accum.
// part: [N*H*SPLIT][1056]
// ---------------------------------------------------------------------------
__global__ __launch_bounds__(256)
void kv_partial(const u16* __restrict__ Kf, const u16* __restrict__ Vf,
                float* __restrict__ part)
{
    int b  = blockIdx.x;
    int s  = b & (KV_SPLIT - 1);
    int nh = b / KV_SPLIT;
    int h  = nh & (N_HEAD - 1);
    int n  = nh / N_HEAD;
    int t  = threadIdx.x;

    __shared__ __align__(16) float Ks[16][D_H];
    __shared__ __align__(16) float Vs[16][D_H];

    const int d   = t >> 3;
    const int dv0 = (t & 7) * 4;
    const int lr  = t >> 4;         // 0..15 (staging row)
    const int lc  = (t & 15) * 2;   // staging col (pairs)
    const size_t base = ((size_t)n * L_SEQ) * C_DIM + h * D_H;

    float a0 = 0, a1 = 0, a2 = 0, a3 = 0, asum = 0;
    const int CH = L_SEQ / KV_SPLIT;
    for (int l = s * CH; l < s * CH + CH; l += 16) {
        __syncthreads();
        u32 ku = *(const u32*)&Kf[base + (size_t)(l + lr) * C_DIM + lc];
        u32 vu = *(const u32*)&Vf[base + (size_t)(l + lr) * C_DIM + lc];
        Ks[lr][lc] = bf2f(ku & 0xffff); Ks[lr][lc + 1] = bf2f(ku >> 16);
        Vs[lr][lc] = bf2f(vu & 0xffff); Vs[lr][lc + 1] = bf2f(vu >> 16);
        __syncthreads();
        #pragma unroll
        for (int i = 0; i < 16; ++i) {
            float kv = Ks[i][d];
            float4 vv = *(const float4*)&Vs[i][dv0];
            a0 = fmaf(kv, vv.x, a0);
            a1 = fmaf(kv, vv.y, a1);
            a2 = fmaf(kv, vv.z, a2);
            a3 = fmaf(kv, vv.w, a3);
            asum += kv;
        }
    }
    float* p = part + (size_t)b * 1056;
    p[d * D_H + dv0 + 0] = a0;
    p[d * D_H + dv0 + 1] = a1;
    p[d * D_H + dv0 + 2] = a2;
    p[d * D_H + dv0 + 3] = a3;
    if ((t & 7) == 0) p[1024 + d] = asum;
}

__global__ __launch_bounds__(256)
void kv_final(const float* __restrict__ part, float* __restrict__ KV,
              float* __restrict__ Ksum)
{
    int nh = blockIdx.x;
    int t  = threadIdx.x;
    float ax = 0, ay = 0, az = 0, aw = 0, ssum = 0;
    const float* p0 = part + (size_t)nh * KV_SPLIT * 1056;
    for (int s = 0; s < KV_SPLIT; ++s) {
        const float* p = p0 + (size_t)s * 1056;
        float4 v = *(const float4*)&p[t * 4];
        ax += v.x; ay += v.y; az += v.z; aw += v.w;
        if (t < D_H) ssum += p[1024 + t];
    }
    float4 o = make_float4(ax, ay, az, aw);
    *(float4*)&KV[(size_t)nh * 1024 + t * 4] = o;
    if (t < D_H) Ksum[nh * D_H + t] = ssum;
}

// ---------------------------------------------------------------------------
// msg[n,l,h,dv] = (sum_d Q[d] * KV[d][dv]) * Z * L ;  Z = 1/(Q.Ksum + eps)
// ---------------------------------------------------------------------------
__global__ __launch_bounds__(256)
void attn_msg(const u16* __restrict__ Qf, const float* __restrict__ KV,
              const float* __restrict__ Ksum, u16* __restrict__ msg)
{
    int token = blockIdx.x;
    int n = token / L_SEQ;
    int t = threadIdx.x;
    int h = t >> 5, dv = t & 31;

    __shared__ float Qs[C_DIM];
    __shared__ float Ss[C_DIM];
    Qs[t] = bf2f(Qf[(size_t)token * C_DIM + t]);
    Ss[t] = Ksum[(size_t)n * C_DIM + t];
    __syncthreads();

    const float* qrow = &Qs[h * D_H];
    const float* srow = &Ss[h * D_H];
    float zden = 0.f;
    #pragma unroll
    for (int d = 0; d < D_H; ++d) zden = fmaf(qrow[d], srow[d], zden);
    float z = 1.0f / (zden + 1e-6f);

    const float* kvp = KV + (((size_t)n * N_HEAD + h) * D_H) * D_H + dv;
    float sacc = 0.f;
    #pragma unroll
    for (int d = 0; d < D_H; ++d) sacc = fmaf(qrow[d], kvp[d * D_H], sacc);

    msg[(size_t)token * C_DIM + t] = f2bf(sacc * z * (float)L_SEQ);
}

// ---------------------------------------------------------------------------
// LayerNorm rows of 256, bf16 input. FINAL: out f32 = LN + x residual.
// else: out bf16.
// ---------------------------------------------------------------------------
template<bool FINAL>
__global__ __launch_bounds__(256)
void ln_rows_bf(const u16* __restrict__ X, const float* __restrict__ g,
                const float* __restrict__ b, const float* __restrict__ xres,
                void* __restrict__ Y)
{
    int row  = blockIdx.x * 4 + (threadIdx.x >> 6);
    int lane = threadIdx.x & 63;
    uint2 u = *(const uint2*)(X + (size_t)row * C_DIM + lane * 4);
    float v0 = bf2f(u.x & 0xffff), v1 = bf2f(u.x >> 16);
    float v2 = bf2f(u.y & 0xffff), v3 = bf2f(u.y >> 16);
    float s  = v0 + v1 + v2 + v3;
    float s2 = v0 * v0 + v1 * v1 + v2 * v2 + v3 * v3;
    #pragma unroll
    for (int off = 1; off < 64; off <<= 1) {
        s  += __shfl_xor(s, off);
        s2 += __shfl_xor(s2, off);
    }
    float mu  = s * (1.0f / C_DIM);
    float var = s2 * (1.0f / C_DIM) - mu * mu;
    float rstd = rsqrtf(var + 1e-5f);
    float4 gv = *(const float4*)&g[lane * 4];
    float4 bv = *(const float4*)&b[lane * 4];
    float o0 = (v0 - mu) * rstd * gv.x + bv.x;
    float o1 = (v1 - mu) * rstd * gv.y + bv.y;
    float o2 = (v2 - mu) * rstd * gv.z + bv.z;
    float o3 = (v3 - mu) * rstd * gv.w + bv.w;
    if (FINAL) {
        float4 xv = *(const float4*)&xres[(size_t)row * C_DIM + lane * 4];
        float4 o = make_float4(o0 + xv.x, o1 + xv.y, o2 + xv.z, o3 + xv.w);
        *(float4*)((float*)Y + (size_t)row * C_DIM + lane * 4) = o;
    } else {
        uint2 o;
        o.x = (u32)f2bf(o0) | ((u32)f2bf(o1) << 16);
        o.y = (u32)f2bf(o2) | ((u32)f2bf(o3) << 16);
        *(uint2*)((u16*)Y + (size_t)row * C_DIM + lane * 4) = o;
    }
}

// ---------------------------------------------------------------------------
extern "C" void kernel_launch(void* const* d_in, const int* in_sizes, int n_in,
                              void* d_out, int out_size, void* d_ws, size_t ws_size,
                              hipStream_t stream)
{
    const float* x  = (const float*)d_in[0];
    const float* Wq = (const float*)d_in[1];
    const float* Wk = (const float*)d_in[2];
    const float* Wv = (const float*)d_in[3];
    const float* Wm = (const float*)d_in[4];
    const float* W1 = (const float*)d_in[5];
    const float* W2 = (const float*)d_in[6];
    const float* g1 = (const float*)d_in[7];
    const float* b1 = (const float*)d_in[8];
    const float* g2 = (const float*)d_in[9];
    const float* b2 = (const float*)d_in[10];
    float* out = (float*)d_out;

    const size_t SLAB = (size_t)M_ROWS * C_DIM;   // 16,777,216 elems
    u16* xb = (u16*)d_ws;
    u16* q  = xb + SLAB;
    u16* k  = q + SLAB;
    u16* v  = k + SLAB;
    // liveness reuse:
    u16* msg = k;          // after kv reduction
    u16* m1  = v;          // after kv reduction
    u16* ln1 = q;          // after attn_msg
    u16* h   = k;          // spans k+v slabs (64MB bf16 M x 512)
    u16* mlp = q;          // after W1 gemm
    // weights (transposed bf16)
    u16* wqt = v + SLAB;
    u16* wkt = wqt + 256 * 256;
    u16* wvt = wkt + 256 * 256;
    u16* wmt = wvt + 256 * 256;
    u16* w1t = wmt + 256 * 256;     // 512*512
    u16* w2t = w1t + 512 * 512;     // 256*512
    float* KV   = (float*)(w2t + 256 * 512);
    float* Ksum = KV + (size_t)N_BATCH * N_HEAD * D_H * D_H;
    float* part = Ksum + (size_t)N_BATCH * N_HEAD * D_H;

    dim3 blk(256);
    const float invL = 1.0f / (float)L_SEQ;

    // ---- converts ----
    f32_to_bf16_k<<<2048, blk, 0, stream>>>(x, xb, (int)(SLAB / 8));
    w_transpose_bf16<<<dim3(8, 8),   blk, 0, stream>>>(Wq, wqt, 256, 256);
    w_transpose_bf16<<<dim3(8, 8),   blk, 0, stream>>>(Wk, wkt, 256, 256);
    w_transpose_bf16<<<dim3(8, 8),   blk, 0, stream>>>(Wv, wvt, 256, 256);
    w_transpose_bf16<<<dim3(8, 8),   blk, 0, stream>>>(Wm, wmt, 256, 256);
    w_transpose_bf16<<<dim3(16, 16), blk, 0, stream>>>(W1, w1t, 512, 512);
    w_transpose_bf16<<<dim3(8, 16),  blk, 0, stream>>>(W2, w2t, 512, 256);

    // ---- projections ----
    dim3 gp(C_DIM / 128, M_ROWS / 128);
    gemm_bf16<1><<<gp, blk, 0, stream>>>(xb, xb, 256, 256, 256, wqt, 256, q, 256, 256, 1.f);
    gemm_bf16<1><<<gp, blk, 0, stream>>>(xb, xb, 256, 256, 256, wkt, 256, k, 256, 256, 1.f);
    gemm_bf16<2><<<gp, blk, 0, stream>>>(xb, xb, 256, 256, 256, wvt, 256, v, 256, 256, invL);

    // ---- KV reduction ----
    kv_partial<<<N_BATCH * N_HEAD * KV_SPLIT, blk, 0, stream>>>(k, v, part);
    kv_final<<<N_BATCH * N_HEAD, blk, 0, stream>>>(part, KV, Ksum);

    // ---- attention message ----
    attn_msg<<<M_ROWS, blk, 0, stream>>>(q, KV, Ksum, msg);

    // ---- merge heads + LN1 ----
    gemm_bf16<0><<<gp, blk, 0, stream>>>(msg, msg, 256, 256, 256, wmt, 256, m1, 256, 256, 1.f);
    ln_rows_bf<false><<<M_ROWS / 4, blk, 0, stream>>>(m1, g1, b1, nullptr, (void*)ln1);

    // ---- MLP ----
    dim3 g1d(512 / 128, M_ROWS / 128);
    gemm_bf16<3><<<g1d, blk, 0, stream>>>(xb, ln1, 256, 256, 256, w1t, 512, h, 512, 512, 1.f);
    dim3 g2d(C_DIM / 128, M_ROWS / 128);
    gemm_bf16<0><<<g2d, blk, 0, stream>>>(h, h, 512, 512, 512, w2t, 512, mlp, 256, 512, 1.f);

    // ---- LN2 + residual ----
    ln_rows_bf<true><<<M_ROWS / 4, blk, 0, stream>>>(mlp, g2, b2, x, out);
}